// Round 9
// baseline (767.100 us; speedup 1.0000x reference)
//
#include <hip/hip_runtime.h>
#include <cstdint>
#include <cstddef>

#define D 64
#define SMAX 24

typedef __attribute__((ext_vector_type(8))) short short8;
typedef __attribute__((ext_vector_type(4))) float floatx4;
typedef __attribute__((ext_vector_type(4))) _Float16 half4v;

__device__ inline unsigned short f2bf(float f) {   // RNE fp32 -> bf16
    unsigned u = __float_as_uint(f);
    unsigned r = 0x7FFFu + ((u >> 16) & 1u);
    return (unsigned short)((u + r) >> 16);
}
__device__ inline float bf2f(unsigned short h) {
    return __uint_as_float(((unsigned)h) << 16);
}

// ---------------- bucket-partition CSR build ----------------

__global__ void k_hist(const int* __restrict__ col, int* __restrict__ ghist,
                       int E, int NBK) {
    extern __shared__ int lh[];
    int t = threadIdx.x;
    for (int i = t; i < NBK; i += 256) lh[i] = 0;
    __syncthreads();
    int base = blockIdx.x * 8192;
    int end = base + 8192; if (end > E) end = E;
    for (int e = base + t; e < end; e += 256) atomicAdd(&lh[col[e] >> 8], 1);
    __syncthreads();
    for (int i = t; i < NBK; i += 256) if (lh[i]) atomicAdd(&ghist[i], lh[i]);
}

__global__ void k_bscan(const int* __restrict__ ghist, int* __restrict__ bstart,
                        int* __restrict__ gcur, int* __restrict__ offs,
                        int NBK, int N, int E) {
    __shared__ int s[512];
    int t = threadIdx.x;
    int v = (t < NBK) ? ghist[t] : 0;
    s[t] = v; __syncthreads();
    for (int off = 1; off < 512; off <<= 1) {
        int x = (t >= off) ? s[t - off] : 0;
        __syncthreads();
        s[t] += x;
        __syncthreads();
    }
    int excl = s[t] - v;
    if (t < NBK) { bstart[t] = excl; gcur[t] = excl; }
    if (t == 0) { bstart[NBK] = E; offs[N] = E; }
}

__global__ __launch_bounds__(256) void k_part(const int* __restrict__ row,
                                              const int* __restrict__ col,
                                              int* __restrict__ gcur,
                                              int2* __restrict__ part,
                                              int E, int NBK) {
    extern __shared__ int sm[];
    int* lcnt = sm;
    int* lbase = sm + NBK;
    int t = threadIdx.x;
    for (int i = t; i < NBK; i += 256) lcnt[i] = 0;
    __syncthreads();
    int base = blockIdx.x * 8192;
    int end = base + 8192; if (end > E) end = E;
    for (int e = base + t; e < end; e += 256) atomicAdd(&lcnt[col[e] >> 8], 1);
    __syncthreads();
    for (int i = t; i < NBK; i += 256) {
        int c = lcnt[i];
        lbase[i] = c ? atomicAdd(&gcur[i], c) : 0;
    }
    __syncthreads();
    for (int i = t; i < NBK; i += 256) lcnt[i] = 0;
    __syncthreads();
    for (int e = base + t; e < end; e += 256) {
        int c = col[e];
        int b = c >> 8;
        int p = lbase[b] + atomicAdd(&lcnt[b], 1);
        part[p] = make_int2(row[e], c);
    }
}

__global__ __launch_bounds__(256) void k_bucket(const int2* __restrict__ part,
                                                const int* __restrict__ bstart,
                                                int* __restrict__ offs,
                                                float* __restrict__ dis,
                                                int* __restrict__ csrc, int N) {
    __shared__ int ncnt[256];
    __shared__ int s[256];
    __shared__ int lcur[256];
    int b = blockIdx.x;
    int t = threadIdx.x;
    int n0 = b << 8;
    int e0 = bstart[b], e1 = bstart[b + 1];
    ncnt[t] = 0;
    __syncthreads();
    for (int e = e0 + t; e < e1; e += 256) {
        int2 pr = part[e];
        atomicAdd(&ncnt[pr.y & 255], 1);
    }
    __syncthreads();
    int v = ncnt[t];
    s[t] = v; __syncthreads();
    for (int off = 1; off < 256; off <<= 1) {
        int x = (t >= off) ? s[t - off] : 0;
        __syncthreads();
        s[t] += x;
        __syncthreads();
    }
    int excl = s[t] - v;
    int node = n0 + t;
    if (node < N) {
        offs[node] = e0 + excl;
        dis[node] = rsqrtf((float)(v + 1));
    }
    lcur[t] = excl;
    __syncthreads();
    for (int e = e0 + t; e < e1; e += 256) {
        int2 pr = part[e];
        int p = atomicAdd(&lcur[pr.y & 255], 1);
        csrc[e0 + p] = pr.x;
    }
}

// graph boundaries
__global__ void k_gb(const int* __restrict__ batch, int* __restrict__ gstart,
                     int N, int G) {
    int g = threadIdx.x;
    if (g > G) return;
    int lo = 0, hi = N;
    while (lo < hi) {
        int mid = (lo + hi) >> 1;
        if (batch[mid] < g) lo = mid + 1; else hi = mid;
    }
    gstart[g] = lo;
}

// fold BN (eval) + conv bias into per-channel scale/shift
__global__ void k_bnprep(const float* __restrict__ cb, const float* __restrict__ g,
                         const float* __restrict__ be, const float* __restrict__ mu,
                         const float* __restrict__ var, float* __restrict__ sc,
                         float* __restrict__ sh, int LD) {
    int i = blockIdx.x * 256 + threadIdx.x;
    if (i < LD) {
        float s = g[i] * rsqrtf(var[i] + 1e-5f);
        sc[i] = s;
        sh[i] = (cb[i] - mu[i]) * s + be[i];
    }
}

// split fp32 weights into bf16 hi/lo, packed in MFMA fragment order
__global__ void k_wpack(const float* __restrict__ B, unsigned short* __restrict__ hiP,
                        unsigned short* __restrict__ loP, int K, int Nc, int nshift) {
    int idx = blockIdx.x * 256 + threadIdx.x;
    if (idx >= K * Nc) return;
    int k = idx >> nshift;
    int n = idx & (Nc - 1);
    float a = B[idx];
    unsigned b = __float_as_uint(a);
    unsigned hb = b & 0xFFFF0000u;
    float ah = __uint_as_float(hb);
    float al = a - ah;
    int c = k >> 5;
    int ntile = n >> 6;
    int j = (n & 63) >> 4;
    int lane = ((k & 31) >> 3) * 16 + (n & 15);
    int kidx = k & 7;
    size_t o = ((((size_t)c * (Nc >> 6) + ntile) * 4 + j) * 64 + lane) * 8 + kidx;
    hiP[o] = (unsigned short)(hb >> 16);
    loP[o] = (unsigned short)(__float_as_uint(al) >> 16);
}

// ---------------- conv GEMM: xw' = fp16((A @ W) * dis[row]),  K=D=64 ----------------

__global__ __launch_bounds__(256) void k_conv(const float* __restrict__ A, int lda,
                                              const float* __restrict__ W,
                                              const float* __restrict__ dis,
                                              _Float16* __restrict__ out, int N) {
    __shared__ float At[64][68];
    __shared__ float Wl[64][64];
    int t = threadIdx.x;
    int bm = blockIdx.x * 64;
    {
        int row = t >> 2, kc = (t & 3) * 16;
        int r = bm + row;
        float v[16];
        if (r < N) {
            const float* p = A + (size_t)r * lda + kc;
#pragma unroll
            for (int j = 0; j < 16; j += 4) {
                float4 x = *(const float4*)(p + j);
                v[j] = x.x; v[j + 1] = x.y; v[j + 2] = x.z; v[j + 3] = x.w;
            }
        } else {
#pragma unroll
            for (int j = 0; j < 16; ++j) v[j] = 0.f;
        }
#pragma unroll
        for (int j = 0; j < 16; ++j) At[kc + j][row] = v[j];
        const float* wp = W + row * 64 + kc;
#pragma unroll
        for (int j = 0; j < 16; j += 4)
            *(float4*)&Wl[row][kc + j] = *(const float4*)(wp + j);
    }
    __syncthreads();
    int m0 = (t & 15) * 4, n0 = (t >> 4) * 4;
    float acc[4][4];
#pragma unroll
    for (int i = 0; i < 4; ++i)
#pragma unroll
        for (int j = 0; j < 4; ++j) acc[i][j] = 0.f;
#pragma unroll 8
    for (int kk = 0; kk < 64; ++kk) {
        float4 a = *(const float4*)&At[kk][m0];
        float4 b = *(const float4*)&Wl[kk][n0];
        float av[4] = {a.x, a.y, a.z, a.w};
        float bv[4] = {b.x, b.y, b.z, b.w};
#pragma unroll
        for (int i = 0; i < 4; ++i)
#pragma unroll
            for (int j = 0; j < 4; ++j) acc[i][j] = fmaf(av[i], bv[j], acc[i][j]);
    }
#pragma unroll
    for (int i = 0; i < 4; ++i) {
        int r = bm + m0 + i;
        if (r < N) {
            float dv = dis[r];
            half4v o;
            o.x = (_Float16)(acc[i][0] * dv);
            o.y = (_Float16)(acc[i][1] * dv);
            o.z = (_Float16)(acc[i][2] * dv);
            o.w = (_Float16)(acc[i][3] * dv);
            *(half4v*)&out[(size_t)r * 64 + n0] = o;
        }
    }
}

// ---------------- aggregation: one node per wave, fp16 gathers + packed fp16 adds ----------------

__global__ __launch_bounds__(256) void k_agg(const _Float16* __restrict__ xw,
                                             const int* __restrict__ offs,
                                             const int* __restrict__ src,
                                             const float* __restrict__ dis,
                                             const float* __restrict__ sc,
                                             const float* __restrict__ sh,
                                             const float* __restrict__ skip,
                                             float* __restrict__ out,
                                             int ld,
                                             unsigned short* __restrict__ outb,
                                             int N) {
    int t = threadIdx.x;
    int lane = t & 63;
    int w = t >> 6;
    int v = blockIdx.x * 4 + w;
    if (v >= N) return;
    int es = lane >> 4;         // edge slot 0..3
    int f4 = lane & 15;         // 4-channel group
    int c0 = f4 * 4;
    const _Float16* xp = xw + c0;
    half4v hacc0 = (half4v)(_Float16)0.f;
    half4v hacc1 = (half4v)(_Float16)0.f;
    half4v hacc2 = (half4v)(_Float16)0.f;
    half4v hacc3 = (half4v)(_Float16)0.f;
    int e0 = offs[v], e1 = offs[v + 1];
    int deg = e1 - e0;
    int k = 0;
    for (; k + 16 <= deg; k += 16) {
        int ld16 = (lane < 16) ? src[e0 + k + lane] : 0;
        int s0 = __shfl(ld16, es);
        int s1 = __shfl(ld16, es + 4);
        int s2 = __shfl(ld16, es + 8);
        int s3 = __shfl(ld16, es + 12);
        half4v m0 = *(const half4v*)(xp + (size_t)s0 * 64);
        half4v m1 = *(const half4v*)(xp + (size_t)s1 * 64);
        half4v m2 = *(const half4v*)(xp + (size_t)s2 * 64);
        half4v m3 = *(const half4v*)(xp + (size_t)s3 * 64);
        hacc0 += m0; hacc1 += m1; hacc2 += m2; hacc3 += m3;
    }
    for (; k + 4 <= deg; k += 4) {
        int ld4 = (lane < 4) ? src[e0 + k + lane] : 0;
        int s0 = __shfl(ld4, es);
        half4v m0 = *(const half4v*)(xp + (size_t)s0 * 64);
        hacc0 += m0;
    }
    int rem = deg - k;
    if (es < rem) {
        int s0 = src[e0 + k + es];
        half4v m0 = *(const half4v*)(xp + (size_t)s0 * 64);
        hacc1 += m0;
    }
    // fp16 partials -> fp32 per-channel
    float ax = (float)hacc0.x + (float)hacc1.x + (float)hacc2.x + (float)hacc3.x;
    float ay = (float)hacc0.y + (float)hacc1.y + (float)hacc2.y + (float)hacc3.y;
    float az = (float)hacc0.z + (float)hacc1.z + (float)hacc2.z + (float)hacc3.z;
    float aw_ = (float)hacc0.w + (float)hacc1.w + (float)hacc2.w + (float)hacc3.w;
    // reduce across the 4 edge slots
    ax += __shfl_xor(ax, 16); ay += __shfl_xor(ay, 16);
    az += __shfl_xor(az, 16); aw_ += __shfl_xor(aw_, 16);
    ax += __shfl_xor(ax, 32); ay += __shfl_xor(ay, 32);
    az += __shfl_xor(az, 32); aw_ += __shfl_xor(aw_, 32);
    if (es == 0) {
        half4v a = *(const half4v*)(xp + (size_t)v * 64);   // self loop
        ax += (float)a.x; ay += (float)a.y; az += (float)a.z; aw_ += (float)a.w;
        float dv = dis[v];
        float4 S = *(const float4*)&sc[c0];
        float4 H = *(const float4*)&sh[c0];
        float y0 = fmaxf(fmaf(ax * dv, S.x, H.x), 0.f);
        float y1 = fmaxf(fmaf(ay * dv, S.y, H.y), 0.f);
        float y2 = fmaxf(fmaf(az * dv, S.z, H.z), 0.f);
        float y3 = fmaxf(fmaf(aw_ * dv, S.w, H.w), 0.f);
        size_t ob = (size_t)v * ld + c0;
        if (skip) {
            const float4 s4 = *(const float4*)(skip + ob);
            y0 += s4.x; y1 += s4.y; y2 += s4.z; y3 += s4.w;
        }
        float4 o; o.x = y0; o.y = y1; o.z = y2; o.w = y3;
        *(float4*)(out + ob) = o;
        ushort4 ob4;
        ob4.x = f2bf(y0); ob4.y = f2bf(y1); ob4.z = f2bf(y2); ob4.w = f2bf(y3);
        *(ushort4*)(outb + ob) = ob4;
    }
}

// ---------------- encoder GEMM: barrier-free, coalesced packed B, SW-pipelined ----------------

__global__ __launch_bounds__(256) void k_encb(const unsigned short* __restrict__ A,
                                              int M, int K, int WN,
                                              const unsigned short* __restrict__ BhiP,
                                              const unsigned short* __restrict__ BloP,
                                              const float* __restrict__ bias,
                                              unsigned short* __restrict__ Cb,
                                              float* __restrict__ Cf, int ldc) {
    int t = threadIdx.x;
    int lane = t & 63;
    int l16 = lane & 15;
    int quad = lane >> 4;
    int w = t >> 6;
    int nw = w % WN;
    int mg = w / WN;
    int BM = 32 * (4 / WN);
    int bm = blockIdx.x * BM + mg * 32;
    int n0 = nw * 64;
    int NC = K >> 5;
    size_t cstr = (size_t)(ldc >> 6) * 2048;

    floatx4 acc[2][4];
#pragma unroll
    for (int i = 0; i < 2; ++i)
#pragma unroll
        for (int j = 0; j < 4; ++j) acc[i][j] = (floatx4)0.f;

    int m0 = bm + l16, m1 = bm + 16 + l16;
    bool v0 = m0 < M, v1 = m1 < M;
    const unsigned short* a0 = A + (size_t)(v0 ? m0 : 0) * K + quad * 8;
    const unsigned short* a1 = A + (size_t)(v1 ? m1 : 0) * K + quad * 8;
    const unsigned short* bp = BhiP + ((size_t)(n0 >> 6) * 4) * 512 + lane * 8;
    size_t loOff = (size_t)(BloP - BhiP);

    short8 a0c = *(const short8*)a0;
    short8 a1c = *(const short8*)a1;
    short8 bhc[4], blc[4];
#pragma unroll
    for (int j = 0; j < 4; ++j) {
        bhc[j] = *(const short8*)(bp + j * 512);
        blc[j] = *(const short8*)(bp + loOff + j * 512);
    }

    for (int c = 0; c < NC; ++c) {
        short8 a0n, a1n, bhn[4], bln[4];
        if (c + 1 < NC) {
            a0n = *(const short8*)(a0 + (c + 1) * 32);
            a1n = *(const short8*)(a1 + (c + 1) * 32);
            const unsigned short* bpn = bp + (size_t)(c + 1) * cstr;
#pragma unroll
            for (int j = 0; j < 4; ++j) {
                bhn[j] = *(const short8*)(bpn + j * 512);
                bln[j] = *(const short8*)(bpn + loOff + j * 512);
            }
        }
#pragma unroll
        for (int j = 0; j < 4; ++j) {
            acc[0][j] = __builtin_amdgcn_mfma_f32_16x16x32_bf16(a0c, blc[j], acc[0][j], 0, 0, 0);
            acc[0][j] = __builtin_amdgcn_mfma_f32_16x16x32_bf16(a0c, bhc[j], acc[0][j], 0, 0, 0);
            acc[1][j] = __builtin_amdgcn_mfma_f32_16x16x32_bf16(a1c, blc[j], acc[1][j], 0, 0, 0);
            acc[1][j] = __builtin_amdgcn_mfma_f32_16x16x32_bf16(a1c, bhc[j], acc[1][j], 0, 0, 0);
        }
        a0c = a0n; a1c = a1n;
#pragma unroll
        for (int j = 0; j < 4; ++j) { bhc[j] = bhn[j]; blc[j] = bln[j]; }
    }

#pragma unroll
    for (int i = 0; i < 2; ++i) {
#pragma unroll
        for (int r = 0; r < 4; ++r) {
            int m = bm + i * 16 + quad * 4 + r;
            if (m < M) {
#pragma unroll
                for (int j = 0; j < 4; ++j) {
                    float y = fmaxf(acc[i][j][r] + bias[n0 + j * 16 + l16], 0.f);
                    size_t idx = (size_t)m * ldc + n0 + j * 16 + l16;
                    if (Cb) Cb[idx] = f2bf(y);
                    else    Cf[idx] = y;
                }
            }
        }
    }
}

// ---------------- graph mean-pool ----------------

__global__ __launch_bounds__(256) void k_pool(const float* __restrict__ h2,
                                              const int* __restrict__ gstart,
                                              float* __restrict__ gsum, int H) {
    int g = blockIdx.x / SMAX;
    int s = blockIdx.x % SMAX;
    int base = gstart[g], end = gstart[g + 1];
    int cnt = end - base;
    if (cnt <= 0) return;
    int per = (cnt + SMAX - 1) / SMAX;
    int n0 = base + s * per;
    int n1 = n0 + per; if (n1 > end) n1 = end;
    if (n0 >= n1) return;
    int t = threadIdx.x;
    int q = t & 31;
    int c = q * 4;
    int sub = t >> 5;
    float4 acc = make_float4(0.f, 0.f, 0.f, 0.f);
    for (int n = n0 + sub; n < n1; n += 8) {
        float4 v = *(const float4*)(h2 + (size_t)n * H + c);
        acc.x += v.x; acc.y += v.y; acc.z += v.z; acc.w += v.w;
    }
    __shared__ float4 red[8][32];
    red[sub][q] = acc;
    __syncthreads();
    if (sub == 0) {
        float4 a = red[0][q];
#pragma unroll
        for (int i = 1; i < 8; ++i) {
            float4 b = red[i][q];
            a.x += b.x; a.y += b.y; a.z += b.z; a.w += b.w;
        }
        atomicAdd(&gsum[(size_t)g * H + c + 0], a.x);
        atomicAdd(&gsum[(size_t)g * H + c + 1], a.y);
        atomicAdd(&gsum[(size_t)g * H + c + 2], a.z);
        atomicAdd(&gsum[(size_t)g * H + c + 3], a.w);
    }
}

// ---------------- decoder ----------------

__global__ void k_dec(const float* __restrict__ gsum, const int* __restrict__ gstart,
                      const float* __restrict__ W1, const float* __restrict__ b1,
                      const float* __restrict__ W2, const float* __restrict__ b2,
                      float* __restrict__ out, int H, int HD) {
    int g = blockIdx.x;
    int t = threadIdx.x;
    float cnt = (float)(gstart[g + 1] - gstart[g]);
    float inv = 1.0f / fmaxf(cnt, 1.0f);
    float hid = b1[t];
    for (int k = 0; k < H; ++k) {
        float gf = gsum[(size_t)g * H + k] * inv;
        hid = fmaf(gf, W1[k * HD + t], hid);
    }
    hid = fmaxf(hid, 0.f);
    float p = hid * W2[t];
    for (int off = 32; off > 0; off >>= 1) p += __shfl_down(p, off);
    if (t == 0) out[g] = p + b2[0];
}

// ---------------- host ----------------

extern "C" void kernel_launch(void* const* d_in, const int* in_sizes, int n_in,
                              void* d_out, int out_size, void* d_ws, size_t ws_size,
                              hipStream_t stream) {
    const float* x     = (const float*)d_in[0];
    const int*   ei    = (const int*)d_in[1];
    const int*   batch = (const int*)d_in[2];
    const float* convW = (const float*)d_in[3];
    const float* convb = (const float*)d_in[4];
    const float* gamma = (const float*)d_in[5];
    const float* beta  = (const float*)d_in[6];
    const float* mean  = (const float*)d_in[7];
    const float* var   = (const float*)d_in[8];
    const float* eW1   = (const float*)d_in[9];
    const float* eb1   = (const float*)d_in[10];
    const float* eW2   = (const float*)d_in[11];
    const float* eb2   = (const float*)d_in[12];
    const float* dW1   = (const float*)d_in[13];
    const float* db1   = (const float*)d_in[14];
    const float* dW2   = (const float*)d_in[15];
    const float* db2   = (const float*)d_in[16];

    int N  = in_sizes[0] / D;
    int E  = in_sizes[1] / 2;
    int L  = in_sizes[3] / (D * D);
    int G  = out_size;
    int LD = L * D;                 // 256
    int H1 = in_sizes[10];          // 256
    int H2 = in_sizes[12];          // 128
    int HD = in_sizes[14];          // 64
    int NBK = (N + 255) >> 8;       // 391

    char* ws = (char*)d_ws;
    size_t off = 0;
    auto alloc = [&](size_t b) -> void* {
        void* p = ws + off;
        off += (b + 255) & ~(size_t)255;
        return p;
    };
    float* local  = (float*)alloc((size_t)N * LD * 4);        // fp32 layer outputs; later h2
    unsigned short* localb = (unsigned short*)alloc((size_t)N * LD * 2);  // bf16 encoder-A copy
    char*  bufB   = (char*)alloc((size_t)N * LD * 2);         // part / xw / h1b
    int*   csrc   = (int*)alloc((size_t)E * 4);
    float* dis    = (float*)alloc((size_t)N * 4);
    int*   offs   = (int*)alloc((size_t)(N + 1) * 4);
    int*   ghist  = (int*)alloc((size_t)NBK * 4);
    int*   bstart = (int*)alloc((size_t)(NBK + 1) * 4);
    int*   gcur   = (int*)alloc((size_t)NBK * 4);
    float* sc     = (float*)alloc((size_t)LD * 4);
    float* sh     = (float*)alloc((size_t)LD * 4);
    float* gsum   = (float*)alloc((size_t)G * H2 * 4);
    int*   gstart = (int*)alloc((size_t)(G + 1) * 4);
    unsigned short* w1hi = (unsigned short*)alloc((size_t)LD * H1 * 2);
    unsigned short* w1lo = (unsigned short*)alloc((size_t)LD * H1 * 2);
    unsigned short* w2hi = (unsigned short*)alloc((size_t)H1 * H2 * 2);
    unsigned short* w2lo = (unsigned short*)alloc((size_t)H1 * H2 * 2);
    int2* part = (int2*)bufB;                    // dead before first k_conv
    _Float16* xw = (_Float16*)bufB;              // fp16 [N][64] message table
    unsigned short* h1b = (unsigned short*)bufB; // bf16 [N][256] after convs
    float* h2 = local;                           // fp32 [N][128]; local dead after enc1

    hipMemsetAsync(ghist, 0, (size_t)NBK * 4, stream);
    hipMemsetAsync(gsum, 0, (size_t)G * H2 * 4, stream);

    int nchunks = (E + 8191) / 8192;
    k_hist<<<nchunks, 256, NBK * 4, stream>>>(ei + E, ghist, E, NBK);
    k_bscan<<<1, 512, 0, stream>>>(ghist, bstart, gcur, offs, NBK, N, E);
    k_part<<<nchunks, 256, 2 * NBK * 4, stream>>>(ei, ei + E, gcur, part, E, NBK);
    k_bucket<<<NBK, 256, 0, stream>>>(part, bstart, offs, dis, csrc, N);
    k_gb<<<1, 128, 0, stream>>>(batch, gstart, N, G);
    k_bnprep<<<(LD + 255) / 256, 256, 0, stream>>>(convb, gamma, beta, mean, var, sc, sh, LD);
    k_wpack<<<(LD * H1 + 255) / 256, 256, 0, stream>>>(eW1, w1hi, w1lo, LD, H1, 8);
    k_wpack<<<(H1 * H2 + 255) / 256, 256, 0, stream>>>(eW2, w2hi, w2lo, H1, H2, 7);

    for (int l = 0; l < L; ++l) {
        const float* Ain = (l == 0) ? x : (local + (size_t)(l - 1) * D);
        int lda = (l == 0) ? D : LD;
        k_conv<<<(N + 63) / 64, 256, 0, stream>>>(Ain, lda, convW + (size_t)l * D * D, dis, xw, N);
        const float* skip = (l % 2 == 0 && l != 0 && l != L - 1) ? (local + (size_t)(l - 2) * D) : nullptr;
        k_agg<<<(N + 3) / 4, 256, 0, stream>>>(xw, offs, csrc, dis, sc + (size_t)l * D,
                                               sh + (size_t)l * D, skip,
                                               local + (size_t)l * D, LD,
                                               localb + (size_t)l * D, N);
    }

    // enc1: A = localb bf16 [N][256] -> h1b bf16 [N][256]. WN=4 -> BM=32.
    k_encb<<<(N + 31) / 32, 256, 0, stream>>>(localb, N, LD, 4, w1hi, w1lo, eb1,
                                              h1b, nullptr, H1);
    // enc2: A = h1b -> h2 fp32 [N][128]. WN=2 -> BM=64.
    k_encb<<<(N + 63) / 64, 256, 0, stream>>>(h1b, N, H1, 2, w2hi, w2lo, eb2,
                                              nullptr, h2, H2);

    k_pool<<<G * SMAX, 256, 0, stream>>>(h2, gstart, gsum, H2);
    k_dec<<<G, HD, 0, stream>>>(gsum, gstart, dW1, db1, dW2, db2, (float*)d_out, H2, HD);
}

// Round 10
// 736.793 us; speedup vs baseline: 1.0411x; 1.0411x over previous
//
#include <hip/hip_runtime.h>
#include <cstdint>
#include <cstddef>

#define D 64
#define SMAX 24

typedef __attribute__((ext_vector_type(8))) short short8;
typedef __attribute__((ext_vector_type(4))) float floatx4;
typedef __attribute__((ext_vector_type(4))) _Float16 half4v;
typedef __attribute__((ext_vector_type(8))) _Float16 half8v;

__device__ inline unsigned short f2bf(float f) {   // RNE fp32 -> bf16
    unsigned u = __float_as_uint(f);
    unsigned r = 0x7FFFu + ((u >> 16) & 1u);
    return (unsigned short)((u + r) >> 16);
}
__device__ inline float bf2f(unsigned short h) {
    return __uint_as_float(((unsigned)h) << 16);
}

// ---------------- bucket-partition CSR build ----------------

__global__ void k_hist(const int* __restrict__ col, int* __restrict__ ghist,
                       int E, int NBK) {
    extern __shared__ int lh[];
    int t = threadIdx.x;
    for (int i = t; i < NBK; i += 256) lh[i] = 0;
    __syncthreads();
    int base = blockIdx.x * 8192;
    int end = base + 8192; if (end > E) end = E;
    for (int e = base + t; e < end; e += 256) atomicAdd(&lh[col[e] >> 8], 1);
    __syncthreads();
    for (int i = t; i < NBK; i += 256) if (lh[i]) atomicAdd(&ghist[i], lh[i]);
}

__global__ void k_bscan(const int* __restrict__ ghist, int* __restrict__ bstart,
                        int* __restrict__ gcur, int* __restrict__ offs,
                        int NBK, int N, int E) {
    __shared__ int s[512];
    int t = threadIdx.x;
    int v = (t < NBK) ? ghist[t] : 0;
    s[t] = v; __syncthreads();
    for (int off = 1; off < 512; off <<= 1) {
        int x = (t >= off) ? s[t - off] : 0;
        __syncthreads();
        s[t] += x;
        __syncthreads();
    }
    int excl = s[t] - v;
    if (t < NBK) { bstart[t] = excl; gcur[t] = excl; }
    if (t == 0) { bstart[NBK] = E; offs[N] = E; }
}

__global__ __launch_bounds__(256) void k_part(const int* __restrict__ row,
                                              const int* __restrict__ col,
                                              int* __restrict__ gcur,
                                              int2* __restrict__ part,
                                              int E, int NBK) {
    extern __shared__ int sm[];
    int* lcnt = sm;
    int* lbase = sm + NBK;
    int t = threadIdx.x;
    for (int i = t; i < NBK; i += 256) lcnt[i] = 0;
    __syncthreads();
    int base = blockIdx.x * 8192;
    int end = base + 8192; if (end > E) end = E;
    for (int e = base + t; e < end; e += 256) atomicAdd(&lcnt[col[e] >> 8], 1);
    __syncthreads();
    for (int i = t; i < NBK; i += 256) {
        int c = lcnt[i];
        lbase[i] = c ? atomicAdd(&gcur[i], c) : 0;
    }
    __syncthreads();
    for (int i = t; i < NBK; i += 256) lcnt[i] = 0;
    __syncthreads();
    for (int e = base + t; e < end; e += 256) {
        int c = col[e];
        int b = c >> 8;
        int p = lbase[b] + atomicAdd(&lcnt[b], 1);
        part[p] = make_int2(row[e], c);
    }
}

__global__ __launch_bounds__(256) void k_bucket(const int2* __restrict__ part,
                                                const int* __restrict__ bstart,
                                                int* __restrict__ offs,
                                                float* __restrict__ dis,
                                                int* __restrict__ csrc, int N) {
    __shared__ int ncnt[256];
    __shared__ int s[256];
    __shared__ int lcur[256];
    int b = blockIdx.x;
    int t = threadIdx.x;
    int n0 = b << 8;
    int e0 = bstart[b], e1 = bstart[b + 1];
    ncnt[t] = 0;
    __syncthreads();
    for (int e = e0 + t; e < e1; e += 256) {
        int2 pr = part[e];
        atomicAdd(&ncnt[pr.y & 255], 1);
    }
    __syncthreads();
    int v = ncnt[t];
    s[t] = v; __syncthreads();
    for (int off = 1; off < 256; off <<= 1) {
        int x = (t >= off) ? s[t - off] : 0;
        __syncthreads();
        s[t] += x;
        __syncthreads();
    }
    int excl = s[t] - v;
    int node = n0 + t;
    if (node < N) {
        offs[node] = e0 + excl;
        dis[node] = rsqrtf((float)(v + 1));
    }
    lcur[t] = excl;
    __syncthreads();
    for (int e = e0 + t; e < e1; e += 256) {
        int2 pr = part[e];
        int p = atomicAdd(&lcur[pr.y & 255], 1);
        csrc[e0 + p] = pr.x;
    }
}

// graph boundaries
__global__ void k_gb(const int* __restrict__ batch, int* __restrict__ gstart,
                     int N, int G) {
    int g = threadIdx.x;
    if (g > G) return;
    int lo = 0, hi = N;
    while (lo < hi) {
        int mid = (lo + hi) >> 1;
        if (batch[mid] < g) lo = mid + 1; else hi = mid;
    }
    gstart[g] = lo;
}

// fold BN (eval) + conv bias into per-channel scale/shift
__global__ void k_bnprep(const float* __restrict__ cb, const float* __restrict__ g,
                         const float* __restrict__ be, const float* __restrict__ mu,
                         const float* __restrict__ var, float* __restrict__ sc,
                         float* __restrict__ sh, int LD) {
    int i = blockIdx.x * 256 + threadIdx.x;
    if (i < LD) {
        float s = g[i] * rsqrtf(var[i] + 1e-5f);
        sc[i] = s;
        sh[i] = (cb[i] - mu[i]) * s + be[i];
    }
}

// split fp32 weights into bf16 hi/lo, packed in MFMA fragment order
__global__ void k_wpack(const float* __restrict__ B, unsigned short* __restrict__ hiP,
                        unsigned short* __restrict__ loP, int K, int Nc, int nshift) {
    int idx = blockIdx.x * 256 + threadIdx.x;
    if (idx >= K * Nc) return;
    int k = idx >> nshift;
    int n = idx & (Nc - 1);
    float a = B[idx];
    unsigned b = __float_as_uint(a);
    unsigned hb = b & 0xFFFF0000u;
    float ah = __uint_as_float(hb);
    float al = a - ah;
    int c = k >> 5;
    int ntile = n >> 6;
    int j = (n & 63) >> 4;
    int lane = ((k & 31) >> 3) * 16 + (n & 15);
    int kidx = k & 7;
    size_t o = ((((size_t)c * (Nc >> 6) + ntile) * 4 + j) * 64 + lane) * 8 + kidx;
    hiP[o] = (unsigned short)(hb >> 16);
    loP[o] = (unsigned short)(__float_as_uint(al) >> 16);
}

// ---------------- conv GEMM: xw' = fp16((A @ W) * dis[row]),  K=D=64 ----------------

__global__ __launch_bounds__(256) void k_conv(const float* __restrict__ A, int lda,
                                              const float* __restrict__ W,
                                              const float* __restrict__ dis,
                                              _Float16* __restrict__ out, int N) {
    __shared__ float At[64][68];
    __shared__ float Wl[64][64];
    int t = threadIdx.x;
    int bm = blockIdx.x * 64;
    {
        int row = t >> 2, kc = (t & 3) * 16;
        int r = bm + row;
        float v[16];
        if (r < N) {
            const float* p = A + (size_t)r * lda + kc;
#pragma unroll
            for (int j = 0; j < 16; j += 4) {
                float4 x = *(const float4*)(p + j);
                v[j] = x.x; v[j + 1] = x.y; v[j + 2] = x.z; v[j + 3] = x.w;
            }
        } else {
#pragma unroll
            for (int j = 0; j < 16; ++j) v[j] = 0.f;
        }
#pragma unroll
        for (int j = 0; j < 16; ++j) At[kc + j][row] = v[j];
        const float* wp = W + row * 64 + kc;
#pragma unroll
        for (int j = 0; j < 16; j += 4)
            *(float4*)&Wl[row][kc + j] = *(const float4*)(wp + j);
    }
    __syncthreads();
    int m0 = (t & 15) * 4, n0 = (t >> 4) * 4;
    float acc[4][4];
#pragma unroll
    for (int i = 0; i < 4; ++i)
#pragma unroll
        for (int j = 0; j < 4; ++j) acc[i][j] = 0.f;
#pragma unroll 8
    for (int kk = 0; kk < 64; ++kk) {
        float4 a = *(const float4*)&At[kk][m0];
        float4 b = *(const float4*)&Wl[kk][n0];
        float av[4] = {a.x, a.y, a.z, a.w};
        float bv[4] = {b.x, b.y, b.z, b.w};
#pragma unroll
        for (int i = 0; i < 4; ++i)
#pragma unroll
            for (int j = 0; j < 4; ++j) acc[i][j] = fmaf(av[i], bv[j], acc[i][j]);
    }
#pragma unroll
    for (int i = 0; i < 4; ++i) {
        int r = bm + m0 + i;
        if (r < N) {
            float dv = dis[r];
            half4v o;
            o.x = (_Float16)(acc[i][0] * dv);
            o.y = (_Float16)(acc[i][1] * dv);
            o.z = (_Float16)(acc[i][2] * dv);
            o.w = (_Float16)(acc[i][3] * dv);
            *(half4v*)&out[(size_t)r * 64 + n0] = o;
        }
    }
}

// ---------------- aggregation: 1 node/wave, 8 edge-slots x 8 chan-lanes, 32 edges/iter ----------------

__global__ __launch_bounds__(256) void k_agg(const _Float16* __restrict__ xw,
                                             const int* __restrict__ offs,
                                             const int* __restrict__ src,
                                             const float* __restrict__ dis,
                                             const float* __restrict__ sc,
                                             const float* __restrict__ sh,
                                             const float* __restrict__ skip,
                                             float* __restrict__ out,
                                             int ld,
                                             unsigned short* __restrict__ outb,
                                             int N) {
    int t = threadIdx.x;
    int lane = t & 63;
    int w = t >> 6;
    int v = blockIdx.x * 4 + w;
    if (v >= N) return;
    int es = lane >> 3;         // edge slot 0..7
    int cg = lane & 7;          // channel group: 8 fp16 channels (16 B)
    int c0 = cg * 8;
    const _Float16* xp = xw + c0;
    half8v h0 = (half8v)(_Float16)0.f;
    half8v h1 = (half8v)(_Float16)0.f;
    half8v h2 = (half8v)(_Float16)0.f;
    half8v h3 = (half8v)(_Float16)0.f;
    int e0 = offs[v], e1 = offs[v + 1];
    int deg = e1 - e0;
    int k = 0;
    int pend = 0;
    if (deg >= 32) pend = (lane < 32) ? src[e0 + lane] : 0;
    for (; k + 32 <= deg; k += 32) {
        int cur = pend;
        if (k + 64 <= deg) pend = (lane < 32) ? src[e0 + k + 32 + lane] : 0;
        int s0 = __shfl(cur, es);
        int s1 = __shfl(cur, es + 8);
        int s2 = __shfl(cur, es + 16);
        int s3 = __shfl(cur, es + 24);
        half8v m0 = *(const half8v*)(xp + (size_t)s0 * 64);
        half8v m1 = *(const half8v*)(xp + (size_t)s1 * 64);
        half8v m2 = *(const half8v*)(xp + (size_t)s2 * 64);
        half8v m3 = *(const half8v*)(xp + (size_t)s3 * 64);
        h0 += m0; h1 += m1; h2 += m2; h3 += m3;
    }
    for (; k + 8 <= deg; k += 8) {
        int ld8 = (lane < 8) ? src[e0 + k + lane] : 0;
        int s0 = __shfl(ld8, es);
        half8v m0 = *(const half8v*)(xp + (size_t)s0 * 64);
        h0 += m0;
    }
    int rem = deg - k;
    if (es < rem) {
        int s0 = src[e0 + k + es];
        half8v m0 = *(const half8v*)(xp + (size_t)s0 * 64);
        h1 += m0;
    }
    half8v hs = (h0 + h1) + (h2 + h3);
    // cross-slot reduction over lanes differing in bits 3..5
    union HU { half8v h; int i4[4]; };
    HU u; u.h = hs;
#pragma unroll
    for (int mask = 8; mask <= 32; mask <<= 1) {
        HU r;
#pragma unroll
        for (int q = 0; q < 4; ++q) r.i4[q] = __shfl_xor(u.i4[q], mask);
        u.h = u.h + r.h;
    }
    if (es == 0) {
        half8v a = *(const half8v*)(xp + (size_t)v * 64);   // self loop
        float dv = dis[v];
        float4 S0 = *(const float4*)&sc[c0];
        float4 S1 = *(const float4*)&sc[c0 + 4];
        float4 H0 = *(const float4*)&sh[c0];
        float4 H1 = *(const float4*)&sh[c0 + 4];
        float sv[8], hv[8];
        sv[0] = S0.x; sv[1] = S0.y; sv[2] = S0.z; sv[3] = S0.w;
        sv[4] = S1.x; sv[5] = S1.y; sv[6] = S1.z; sv[7] = S1.w;
        hv[0] = H0.x; hv[1] = H0.y; hv[2] = H0.z; hv[3] = H0.w;
        hv[4] = H1.x; hv[5] = H1.y; hv[6] = H1.z; hv[7] = H1.w;
        float y[8];
#pragma unroll
        for (int q = 0; q < 8; ++q) {
            float aq = (float)u.h[q] + (float)a[q];
            y[q] = fmaxf(fmaf(aq * dv, sv[q], hv[q]), 0.f);
        }
        size_t ob = (size_t)v * ld + c0;
        if (skip) {
            float4 k0v = *(const float4*)(skip + ob);
            float4 k1v = *(const float4*)(skip + ob + 4);
            y[0] += k0v.x; y[1] += k0v.y; y[2] += k0v.z; y[3] += k0v.w;
            y[4] += k1v.x; y[5] += k1v.y; y[6] += k1v.z; y[7] += k1v.w;
        }
        float4 o0, o1;
        o0.x = y[0]; o0.y = y[1]; o0.z = y[2]; o0.w = y[3];
        o1.x = y[4]; o1.y = y[5]; o1.z = y[6]; o1.w = y[7];
        *(float4*)(out + ob) = o0;
        *(float4*)(out + ob + 4) = o1;
        short8 b8;
#pragma unroll
        for (int q = 0; q < 8; ++q) b8[q] = (short)f2bf(y[q]);
        *(short8*)(outb + ob) = b8;
    }
}

// ---------------- encoder GEMM: barrier-free, packed B, m=64/wave, SW-pipelined ----------------
// C = relu(A @ (Bhi+Blo) + bias). Wave tile m=64 (4 frags) x n=64 (4 frags).
// WN waves across n; BM = 64*(4/WN). 32 MFMA per 32-K chunk amortize the loads.

__global__ __launch_bounds__(256) void k_encb(const unsigned short* __restrict__ A,
                                              int M, int K, int WN,
                                              const unsigned short* __restrict__ BhiP,
                                              const unsigned short* __restrict__ BloP,
                                              const float* __restrict__ bias,
                                              unsigned short* __restrict__ Cb,
                                              float* __restrict__ Cf, int ldc) {
    int t = threadIdx.x;
    int lane = t & 63;
    int l16 = lane & 15;
    int quad = lane >> 4;
    int w = t >> 6;
    int nw = w % WN;
    int mg = w / WN;
    int BM = 64 * (4 / WN);
    int bm = blockIdx.x * BM + mg * 64;
    int n0 = nw * 64;
    int NC = K >> 5;
    size_t cstr = (size_t)(ldc >> 6) * 2048;

    floatx4 acc[4][4];
#pragma unroll
    for (int i = 0; i < 4; ++i)
#pragma unroll
        for (int j = 0; j < 4; ++j) acc[i][j] = (floatx4)0.f;

    const unsigned short* ap[4];
    bool vm[4];
#pragma unroll
    for (int i = 0; i < 4; ++i) {
        int m = bm + i * 16 + l16;
        vm[i] = m < M;
        ap[i] = A + (size_t)(vm[i] ? m : 0) * K + quad * 8;
    }
    const unsigned short* bp = BhiP + ((size_t)(n0 >> 6) * 4) * 512 + lane * 8;
    size_t loOff = (size_t)(BloP - BhiP);

    short8 ac[4], bhc[4], blc[4];
#pragma unroll
    for (int i = 0; i < 4; ++i) ac[i] = *(const short8*)(ap[i]);
#pragma unroll
    for (int j = 0; j < 4; ++j) {
        bhc[j] = *(const short8*)(bp + j * 512);
        blc[j] = *(const short8*)(bp + loOff + j * 512);
    }

    for (int c = 0; c < NC; ++c) {
        short8 an[4], bhn[4], bln[4];
        if (c + 1 < NC) {
#pragma unroll
            for (int i = 0; i < 4; ++i) an[i] = *(const short8*)(ap[i] + (c + 1) * 32);
            const unsigned short* bpn = bp + (size_t)(c + 1) * cstr;
#pragma unroll
            for (int j = 0; j < 4; ++j) {
                bhn[j] = *(const short8*)(bpn + j * 512);
                bln[j] = *(const short8*)(bpn + loOff + j * 512);
            }
        }
#pragma unroll
        for (int i = 0; i < 4; ++i) {
#pragma unroll
            for (int j = 0; j < 4; ++j) {
                acc[i][j] = __builtin_amdgcn_mfma_f32_16x16x32_bf16(ac[i], blc[j], acc[i][j], 0, 0, 0);
                acc[i][j] = __builtin_amdgcn_mfma_f32_16x16x32_bf16(ac[i], bhc[j], acc[i][j], 0, 0, 0);
            }
        }
#pragma unroll
        for (int i = 0; i < 4; ++i) ac[i] = an[i];
#pragma unroll
        for (int j = 0; j < 4; ++j) { bhc[j] = bhn[j]; blc[j] = bln[j]; }
    }

#pragma unroll
    for (int i = 0; i < 4; ++i) {
#pragma unroll
        for (int r = 0; r < 4; ++r) {
            int m = bm + i * 16 + quad * 4 + r;
            if (m < M) {
#pragma unroll
                for (int j = 0; j < 4; ++j) {
                    float y = fmaxf(acc[i][j][r] + bias[n0 + j * 16 + l16], 0.f);
                    size_t idx = (size_t)m * ldc + n0 + j * 16 + l16;
                    if (Cb) Cb[idx] = f2bf(y);
                    else    Cf[idx] = y;
                }
            }
        }
    }
}

// ---------------- graph mean-pool ----------------

__global__ __launch_bounds__(256) void k_pool(const float* __restrict__ h2,
                                              const int* __restrict__ gstart,
                                              float* __restrict__ gsum, int H) {
    int g = blockIdx.x / SMAX;
    int s = blockIdx.x % SMAX;
    int base = gstart[g], end = gstart[g + 1];
    int cnt = end - base;
    if (cnt <= 0) return;
    int per = (cnt + SMAX - 1) / SMAX;
    int n0 = base + s * per;
    int n1 = n0 + per; if (n1 > end) n1 = end;
    if (n0 >= n1) return;
    int t = threadIdx.x;
    int q = t & 31;
    int c = q * 4;
    int sub = t >> 5;
    float4 acc = make_float4(0.f, 0.f, 0.f, 0.f);
    for (int n = n0 + sub; n < n1; n += 8) {
        float4 v = *(const float4*)(h2 + (size_t)n * H + c);
        acc.x += v.x; acc.y += v.y; acc.z += v.z; acc.w += v.w;
    }
    __shared__ float4 red[8][32];
    red[sub][q] = acc;
    __syncthreads();
    if (sub == 0) {
        float4 a = red[0][q];
#pragma unroll
        for (int i = 1; i < 8; ++i) {
            float4 b = red[i][q];
            a.x += b.x; a.y += b.y; a.z += b.z; a.w += b.w;
        }
        atomicAdd(&gsum[(size_t)g * H + c + 0], a.x);
        atomicAdd(&gsum[(size_t)g * H + c + 1], a.y);
        atomicAdd(&gsum[(size_t)g * H + c + 2], a.z);
        atomicAdd(&gsum[(size_t)g * H + c + 3], a.w);
    }
}

// ---------------- decoder ----------------

__global__ void k_dec(const float* __restrict__ gsum, const int* __restrict__ gstart,
                      const float* __restrict__ W1, const float* __restrict__ b1,
                      const float* __restrict__ W2, const float* __restrict__ b2,
                      float* __restrict__ out, int H, int HD) {
    int g = blockIdx.x;
    int t = threadIdx.x;
    float cnt = (float)(gstart[g + 1] - gstart[g]);
    float inv = 1.0f / fmaxf(cnt, 1.0f);
    float hid = b1[t];
    for (int k = 0; k < H; ++k) {
        float gf = gsum[(size_t)g * H + k] * inv;
        hid = fmaf(gf, W1[k * HD + t], hid);
    }
    hid = fmaxf(hid, 0.f);
    float p = hid * W2[t];
    for (int off = 32; off > 0; off >>= 1) p += __shfl_down(p, off);
    if (t == 0) out[g] = p + b2[0];
}

// ---------------- host ----------------

extern "C" void kernel_launch(void* const* d_in, const int* in_sizes, int n_in,
                              void* d_out, int out_size, void* d_ws, size_t ws_size,
                              hipStream_t stream) {
    const float* x     = (const float*)d_in[0];
    const int*   ei    = (const int*)d_in[1];
    const int*   batch = (const int*)d_in[2];
    const float* convW = (const float*)d_in[3];
    const float* convb = (const float*)d_in[4];
    const float* gamma = (const float*)d_in[5];
    const float* beta  = (const float*)d_in[6];
    const float* mean  = (const float*)d_in[7];
    const float* var   = (const float*)d_in[8];
    const float* eW1   = (const float*)d_in[9];
    const float* eb1   = (const float*)d_in[10];
    const float* eW2   = (const float*)d_in[11];
    const float* eb2   = (const float*)d_in[12];
    const float* dW1   = (const float*)d_in[13];
    const float* db1   = (const float*)d_in[14];
    const float* dW2   = (const float*)d_in[15];
    const float* db2   = (const float*)d_in[16];

    int N  = in_sizes[0] / D;
    int E  = in_sizes[1] / 2;
    int L  = in_sizes[3] / (D * D);
    int G  = out_size;
    int LD = L * D;                 // 256
    int H1 = in_sizes[10];          // 256
    int H2 = in_sizes[12];          // 128
    int HD = in_sizes[14];          // 64
    int NBK = (N + 255) >> 8;       // 391

    char* ws = (char*)d_ws;
    size_t off = 0;
    auto alloc = [&](size_t b) -> void* {
        void* p = ws + off;
        off += (b + 255) & ~(size_t)255;
        return p;
    };
    float* local  = (float*)alloc((size_t)N * LD * 4);        // fp32 layer outputs; later h2
    unsigned short* localb = (unsigned short*)alloc((size_t)N * LD * 2);  // bf16 encoder-A copy
    char*  bufB   = (char*)alloc((size_t)N * LD * 2);         // part / xw / h1b
    int*   csrc   = (int*)alloc((size_t)E * 4);
    float* dis    = (float*)alloc((size_t)N * 4);
    int*   offs   = (int*)alloc((size_t)(N + 1) * 4);
    int*   ghist  = (int*)alloc((size_t)NBK * 4);
    int*   bstart = (int*)alloc((size_t)(NBK + 1) * 4);
    int*   gcur   = (int*)alloc((size_t)NBK * 4);
    float* sc     = (float*)alloc((size_t)LD * 4);
    float* sh     = (float*)alloc((size_t)LD * 4);
    float* gsum   = (float*)alloc((size_t)G * H2 * 4);
    int*   gstart = (int*)alloc((size_t)(G + 1) * 4);
    unsigned short* w1hi = (unsigned short*)alloc((size_t)LD * H1 * 2);
    unsigned short* w1lo = (unsigned short*)alloc((size_t)LD * H1 * 2);
    unsigned short* w2hi = (unsigned short*)alloc((size_t)H1 * H2 * 2);
    unsigned short* w2lo = (unsigned short*)alloc((size_t)H1 * H2 * 2);
    int2* part = (int2*)bufB;                    // dead before first k_conv
    _Float16* xw = (_Float16*)bufB;              // fp16 [N][64] message table
    unsigned short* h1b = (unsigned short*)bufB; // bf16 [N][256] after convs
    float* h2 = local;                           // fp32 [N][128]; local dead after enc1

    hipMemsetAsync(ghist, 0, (size_t)NBK * 4, stream);
    hipMemsetAsync(gsum, 0, (size_t)G * H2 * 4, stream);

    int nchunks = (E + 8191) / 8192;
    k_hist<<<nchunks, 256, NBK * 4, stream>>>(ei + E, ghist, E, NBK);
    k_bscan<<<1, 512, 0, stream>>>(ghist, bstart, gcur, offs, NBK, N, E);
    k_part<<<nchunks, 256, 2 * NBK * 4, stream>>>(ei, ei + E, gcur, part, E, NBK);
    k_bucket<<<NBK, 256, 0, stream>>>(part, bstart, offs, dis, csrc, N);
    k_gb<<<1, 128, 0, stream>>>(batch, gstart, N, G);
    k_bnprep<<<(LD + 255) / 256, 256, 0, stream>>>(convb, gamma, beta, mean, var, sc, sh, LD);
    k_wpack<<<(LD * H1 + 255) / 256, 256, 0, stream>>>(eW1, w1hi, w1lo, LD, H1, 8);
    k_wpack<<<(H1 * H2 + 255) / 256, 256, 0, stream>>>(eW2, w2hi, w2lo, H1, H2, 7);

    for (int l = 0; l < L; ++l) {
        const float* Ain = (l == 0) ? x : (local + (size_t)(l - 1) * D);
        int lda = (l == 0) ? D : LD;
        k_conv<<<(N + 63) / 64, 256, 0, stream>>>(Ain, lda, convW + (size_t)l * D * D, dis, xw, N);
        const float* skip = (l % 2 == 0 && l != 0 && l != L - 1) ? (local + (size_t)(l - 2) * D) : nullptr;
        k_agg<<<(N + 3) / 4, 256, 0, stream>>>(xw, offs, csrc, dis, sc + (size_t)l * D,
                                               sh + (size_t)l * D, skip,
                                               local + (size_t)l * D, LD,
                                               localb + (size_t)l * D, N);
    }

    // enc1: A = localb bf16 [N][256] -> h1b bf16 [N][256]. WN=4 -> BM=64.
    k_encb<<<(N + 63) / 64, 256, 0, stream>>>(localb, N, LD, 4, w1hi, w1lo, eb1,
                                              h1b, nullptr, H1);
    // enc2: A = h1b -> h2 fp32 [N][128]. WN=2 -> BM=128.
    k_encb<<<(N + 127) / 128, 256, 0, stream>>>(h1b, N, H1, 2, w2hi, w2lo, eb2,
                                                nullptr, h2, H2);

    k_pool<<<G * SMAX, 256, 0, stream>>>(h2, gstart, gsum, H2);
    k_dec<<<G, HD, 0, stream>>>(gsum, gstart, dW1, db1, dW2, db2, (float*)d_out, H2, HD);
}

// Round 11
// 710.416 us; speedup vs baseline: 1.0798x; 1.0371x over previous
//
#include <hip/hip_runtime.h>
#include <cstdint>
#include <cstddef>

#define D 64
#define SMAX 24

typedef __attribute__((ext_vector_type(8))) short short8;
typedef __attribute__((ext_vector_type(4))) float floatx4;
typedef __attribute__((ext_vector_type(4))) _Float16 half4v;
typedef __attribute__((ext_vector_type(8))) _Float16 half8v;

__device__ inline unsigned short f2bf(float f) {   // RNE fp32 -> bf16
    unsigned u = __float_as_uint(f);
    unsigned r = 0x7FFFu + ((u >> 16) & 1u);
    return (unsigned short)((u + r) >> 16);
}
__device__ inline float bf2f(unsigned short h) {
    return __uint_as_float(((unsigned)h) << 16);
}

// ---------------- bucket-partition CSR build ----------------

__global__ void k_hist(const int* __restrict__ col, int* __restrict__ ghist,
                       int E, int NBK) {
    extern __shared__ int lh[];
    int t = threadIdx.x;
    for (int i = t; i < NBK; i += 256) lh[i] = 0;
    __syncthreads();
    int base = blockIdx.x * 8192;
    int end = base + 8192; if (end > E) end = E;
    for (int e = base + t; e < end; e += 256) atomicAdd(&lh[col[e] >> 8], 1);
    __syncthreads();
    for (int i = t; i < NBK; i += 256) if (lh[i]) atomicAdd(&ghist[i], lh[i]);
}

__global__ void k_bscan(const int* __restrict__ ghist, int* __restrict__ bstart,
                        int* __restrict__ gcur, int* __restrict__ offs,
                        int NBK, int N, int E) {
    __shared__ int s[512];
    int t = threadIdx.x;
    int v = (t < NBK) ? ghist[t] : 0;
    s[t] = v; __syncthreads();
    for (int off = 1; off < 512; off <<= 1) {
        int x = (t >= off) ? s[t - off] : 0;
        __syncthreads();
        s[t] += x;
        __syncthreads();
    }
    int excl = s[t] - v;
    if (t < NBK) { bstart[t] = excl; gcur[t] = excl; }
    if (t == 0) { bstart[NBK] = E; offs[N] = E; }
}

__global__ __launch_bounds__(256) void k_part(const int* __restrict__ row,
                                              const int* __restrict__ col,
                                              int* __restrict__ gcur,
                                              int2* __restrict__ part,
                                              int E, int NBK) {
    extern __shared__ int sm[];
    int* lcnt = sm;
    int* lbase = sm + NBK;
    int t = threadIdx.x;
    for (int i = t; i < NBK; i += 256) lcnt[i] = 0;
    __syncthreads();
    int base = blockIdx.x * 8192;
    int end = base + 8192; if (end > E) end = E;
    for (int e = base + t; e < end; e += 256) atomicAdd(&lcnt[col[e] >> 8], 1);
    __syncthreads();
    for (int i = t; i < NBK; i += 256) {
        int c = lcnt[i];
        lbase[i] = c ? atomicAdd(&gcur[i], c) : 0;
    }
    __syncthreads();
    for (int i = t; i < NBK; i += 256) lcnt[i] = 0;
    __syncthreads();
    for (int e = base + t; e < end; e += 256) {
        int c = col[e];
        int b = c >> 8;
        int p = lbase[b] + atomicAdd(&lcnt[b], 1);
        part[p] = make_int2(row[e], c);
    }
}

__global__ __launch_bounds__(256) void k_bucket(const int2* __restrict__ part,
                                                const int* __restrict__ bstart,
                                                int* __restrict__ offs,
                                                float* __restrict__ dis,
                                                int* __restrict__ csrc, int N) {
    __shared__ int ncnt[256];
    __shared__ int s[256];
    __shared__ int lcur[256];
    int b = blockIdx.x;
    int t = threadIdx.x;
    int n0 = b << 8;
    int e0 = bstart[b], e1 = bstart[b + 1];
    ncnt[t] = 0;
    __syncthreads();
    for (int e = e0 + t; e < e1; e += 256) {
        int2 pr = part[e];
        atomicAdd(&ncnt[pr.y & 255], 1);
    }
    __syncthreads();
    int v = ncnt[t];
    s[t] = v; __syncthreads();
    for (int off = 1; off < 256; off <<= 1) {
        int x = (t >= off) ? s[t - off] : 0;
        __syncthreads();
        s[t] += x;
        __syncthreads();
    }
    int excl = s[t] - v;
    int node = n0 + t;
    if (node < N) {
        offs[node] = e0 + excl;
        dis[node] = rsqrtf((float)(v + 1));
    }
    lcur[t] = excl;
    __syncthreads();
    for (int e = e0 + t; e < e1; e += 256) {
        int2 pr = part[e];
        int p = atomicAdd(&lcur[pr.y & 255], 1);
        csrc[e0 + p] = pr.x;
    }
}

// graph boundaries
__global__ void k_gb(const int* __restrict__ batch, int* __restrict__ gstart,
                     int N, int G) {
    int g = threadIdx.x;
    if (g > G) return;
    int lo = 0, hi = N;
    while (lo < hi) {
        int mid = (lo + hi) >> 1;
        if (batch[mid] < g) lo = mid + 1; else hi = mid;
    }
    gstart[g] = lo;
}

// fold BN (eval) + conv bias into per-channel scale/shift
__global__ void k_bnprep(const float* __restrict__ cb, const float* __restrict__ g,
                         const float* __restrict__ be, const float* __restrict__ mu,
                         const float* __restrict__ var, float* __restrict__ sc,
                         float* __restrict__ sh, int LD) {
    int i = blockIdx.x * 256 + threadIdx.x;
    if (i < LD) {
        float s = g[i] * rsqrtf(var[i] + 1e-5f);
        sc[i] = s;
        sh[i] = (cb[i] - mu[i]) * s + be[i];
    }
}

// split fp32 weights into bf16 hi/lo, packed in MFMA fragment order:
// (k,n) -> chunk c=k/32, ntile=n/64, j=(n&63)>>4, lane=((k&31)>>3)*16+(n&15), kidx=k&7
__global__ void k_wpack(const float* __restrict__ B, unsigned short* __restrict__ hiP,
                        unsigned short* __restrict__ loP, int K, int Nc, int nshift) {
    int idx = blockIdx.x * 256 + threadIdx.x;
    if (idx >= K * Nc) return;
    int k = idx >> nshift;
    int n = idx & (Nc - 1);
    float a = B[idx];
    unsigned b = __float_as_uint(a);
    unsigned hb = b & 0xFFFF0000u;
    float ah = __uint_as_float(hb);
    float al = a - ah;
    int c = k >> 5;
    int ntile = n >> 6;
    int j = (n & 63) >> 4;
    int lane = ((k & 31) >> 3) * 16 + (n & 15);
    int kidx = k & 7;
    size_t o = ((((size_t)c * (Nc >> 6) + ntile) * 4 + j) * 64 + lane) * 8 + kidx;
    hiP[o] = (unsigned short)(hb >> 16);
    loP[o] = (unsigned short)(__float_as_uint(al) >> 16);
}

// bf16-only (RNE) fragment-packed weights (encoder)
__global__ void k_wpackb(const float* __restrict__ B, unsigned short* __restrict__ P,
                         int K, int Nc, int nshift) {
    int idx = blockIdx.x * 256 + threadIdx.x;
    if (idx >= K * Nc) return;
    int k = idx >> nshift;
    int n = idx & (Nc - 1);
    int c = k >> 5;
    int ntile = n >> 6;
    int j = (n & 63) >> 4;
    int lane = ((k & 31) >> 3) * 16 + (n & 15);
    int kidx = k & 7;
    size_t o = ((((size_t)c * (Nc >> 6) + ntile) * 4 + j) * 64 + lane) * 8 + kidx;
    P[o] = f2bf(B[idx]);
}

// cast fp32 -> bf16 (RNE), 8 elems/thread
__global__ void k_cast(const float* __restrict__ x, unsigned short* __restrict__ xb,
                       int n8) {
    int i = blockIdx.x * 256 + threadIdx.x;
    if (i >= n8) return;
    const float4* p = (const float4*)(x + (size_t)i * 8);
    float4 v0 = p[0], v1 = p[1];
    short8 o;
    o[0] = (short)f2bf(v0.x); o[1] = (short)f2bf(v0.y);
    o[2] = (short)f2bf(v0.z); o[3] = (short)f2bf(v0.w);
    o[4] = (short)f2bf(v1.x); o[5] = (short)f2bf(v1.y);
    o[6] = (short)f2bf(v1.z); o[7] = (short)f2bf(v1.w);
    *(short8*)(xb + (size_t)i * 8) = o;
}

// ---------------- conv GEMM via MFMA: xw' = fp16((A_bf16 @ (Whi+Wlo)) * dis[row]) ----------------
// K=64 (2 chunks, fully unrolled). Wave tile m=32 x n=64. Block = 4 waves -> BM=128.

__global__ __launch_bounds__(256) void k_convm(const unsigned short* __restrict__ A, int lda,
                                               const unsigned short* __restrict__ Whi,
                                               const unsigned short* __restrict__ Wlo,
                                               const float* __restrict__ dis,
                                               _Float16* __restrict__ out, int N) {
    int t = threadIdx.x;
    int lane = t & 63;
    int l16 = lane & 15;
    int quad = lane >> 4;
    int w = t >> 6;
    int bm = blockIdx.x * 128 + w * 32;

    floatx4 acc[2][4];
#pragma unroll
    for (int i = 0; i < 2; ++i)
#pragma unroll
        for (int j = 0; j < 4; ++j) acc[i][j] = (floatx4)0.f;

    int r0 = bm + l16; if (r0 > N - 1) r0 = N - 1;
    int r1 = bm + 16 + l16; if (r1 > N - 1) r1 = N - 1;
    const unsigned short* a0 = A + (size_t)r0 * lda + quad * 8;
    const unsigned short* a1 = A + (size_t)r1 * lda + quad * 8;
    const unsigned short* bp = Whi + lane * 8;
    size_t loOff = (size_t)(Wlo - Whi);

    short8 a0c[2], a1c[2], bh[2][4], bl[2][4];
#pragma unroll
    for (int c = 0; c < 2; ++c) {
        a0c[c] = *(const short8*)(a0 + c * 32);
        a1c[c] = *(const short8*)(a1 + c * 32);
#pragma unroll
        for (int j = 0; j < 4; ++j) {
            bh[c][j] = *(const short8*)(bp + c * 2048 + j * 512);
            bl[c][j] = *(const short8*)(bp + loOff + c * 2048 + j * 512);
        }
    }
#pragma unroll
    for (int c = 0; c < 2; ++c) {
#pragma unroll
        for (int j = 0; j < 4; ++j) {
            acc[0][j] = __builtin_amdgcn_mfma_f32_16x16x32_bf16(a0c[c], bl[c][j], acc[0][j], 0, 0, 0);
            acc[0][j] = __builtin_amdgcn_mfma_f32_16x16x32_bf16(a0c[c], bh[c][j], acc[0][j], 0, 0, 0);
            acc[1][j] = __builtin_amdgcn_mfma_f32_16x16x32_bf16(a1c[c], bl[c][j], acc[1][j], 0, 0, 0);
            acc[1][j] = __builtin_amdgcn_mfma_f32_16x16x32_bf16(a1c[c], bh[c][j], acc[1][j], 0, 0, 0);
        }
    }
#pragma unroll
    for (int i = 0; i < 2; ++i) {
#pragma unroll
        for (int r = 0; r < 4; ++r) {
            int m = bm + i * 16 + quad * 4 + r;
            if (m < N) {
                float dv = dis[m];
                _Float16* op = out + (size_t)m * 64 + l16;
#pragma unroll
                for (int j = 0; j < 4; ++j)
                    op[j * 16] = (_Float16)(acc[i][j][r] * dv);
            }
        }
    }
}

// ---------------- aggregation: 1 node/wave, 8 edge-slots x 8 chan-lanes, 32 edges/iter ----------------

__global__ __launch_bounds__(256) void k_agg(const _Float16* __restrict__ xw,
                                             const int* __restrict__ offs,
                                             const int* __restrict__ src,
                                             const float* __restrict__ dis,
                                             const float* __restrict__ sc,
                                             const float* __restrict__ sh,
                                             const float* __restrict__ skip,
                                             float* __restrict__ out,
                                             int ld,
                                             unsigned short* __restrict__ outb,
                                             int N) {
    int t = threadIdx.x;
    int lane = t & 63;
    int w = t >> 6;
    int v = blockIdx.x * 4 + w;
    if (v >= N) return;
    int es = lane >> 3;         // edge slot 0..7
    int cg = lane & 7;          // channel group: 8 fp16 channels (16 B)
    int c0 = cg * 8;
    const _Float16* xp = xw + c0;
    half8v h0 = (half8v)(_Float16)0.f;
    half8v h1 = (half8v)(_Float16)0.f;
    half8v h2 = (half8v)(_Float16)0.f;
    half8v h3 = (half8v)(_Float16)0.f;
    int e0 = offs[v], e1 = offs[v + 1];
    int deg = e1 - e0;
    int k = 0;
    int pend = 0;
    if (deg >= 32) pend = (lane < 32) ? src[e0 + lane] : 0;
    for (; k + 32 <= deg; k += 32) {
        int cur = pend;
        if (k + 64 <= deg) pend = (lane < 32) ? src[e0 + k + 32 + lane] : 0;
        int s0 = __shfl(cur, es);
        int s1 = __shfl(cur, es + 8);
        int s2 = __shfl(cur, es + 16);
        int s3 = __shfl(cur, es + 24);
        half8v m0 = *(const half8v*)(xp + (size_t)s0 * 64);
        half8v m1 = *(const half8v*)(xp + (size_t)s1 * 64);
        half8v m2 = *(const half8v*)(xp + (size_t)s2 * 64);
        half8v m3 = *(const half8v*)(xp + (size_t)s3 * 64);
        h0 += m0; h1 += m1; h2 += m2; h3 += m3;
    }
    for (; k + 8 <= deg; k += 8) {
        int ld8 = (lane < 8) ? src[e0 + k + lane] : 0;
        int s0 = __shfl(ld8, es);
        half8v m0 = *(const half8v*)(xp + (size_t)s0 * 64);
        h0 += m0;
    }
    int rem = deg - k;
    if (es < rem) {
        int s0 = src[e0 + k + es];
        half8v m0 = *(const half8v*)(xp + (size_t)s0 * 64);
        h1 += m0;
    }
    half8v hs = (h0 + h1) + (h2 + h3);
    union HU { half8v h; int i4[4]; };
    HU u; u.h = hs;
#pragma unroll
    for (int mask = 8; mask <= 32; mask <<= 1) {
        HU r;
#pragma unroll
        for (int q = 0; q < 4; ++q) r.i4[q] = __shfl_xor(u.i4[q], mask);
        u.h = u.h + r.h;
    }
    if (es == 0) {
        half8v a = *(const half8v*)(xp + (size_t)v * 64);   // self loop
        float dv = dis[v];
        float4 S0 = *(const float4*)&sc[c0];
        float4 S1 = *(const float4*)&sc[c0 + 4];
        float4 H0 = *(const float4*)&sh[c0];
        float4 H1 = *(const float4*)&sh[c0 + 4];
        float sv[8], hv[8];
        sv[0] = S0.x; sv[1] = S0.y; sv[2] = S0.z; sv[3] = S0.w;
        sv[4] = S1.x; sv[5] = S1.y; sv[6] = S1.z; sv[7] = S1.w;
        hv[0] = H0.x; hv[1] = H0.y; hv[2] = H0.z; hv[3] = H0.w;
        hv[4] = H1.x; hv[5] = H1.y; hv[6] = H1.z; hv[7] = H1.w;
        float y[8];
#pragma unroll
        for (int q = 0; q < 8; ++q) {
            float aq = (float)u.h[q] + (float)a[q];
            y[q] = fmaxf(fmaf(aq * dv, sv[q], hv[q]), 0.f);
        }
        size_t ob = (size_t)v * ld + c0;
        if (skip) {
            float4 k0v = *(const float4*)(skip + ob);
            float4 k1v = *(const float4*)(skip + ob + 4);
            y[0] += k0v.x; y[1] += k0v.y; y[2] += k0v.z; y[3] += k0v.w;
            y[4] += k1v.x; y[5] += k1v.y; y[6] += k1v.z; y[7] += k1v.w;
        }
        float4 o0, o1;
        o0.x = y[0]; o0.y = y[1]; o0.z = y[2]; o0.w = y[3];
        o1.x = y[4]; o1.y = y[5]; o1.z = y[6]; o1.w = y[7];
        *(float4*)(out + ob) = o0;
        *(float4*)(out + ob + 4) = o1;
        short8 b8;
#pragma unroll
        for (int q = 0; q < 8; ++q) b8[q] = (short)f2bf(y[q]);
        *(short8*)(outb + ob) = b8;
    }
}

// ---------------- encoder GEMM: barrier-free, packed bf16 B, m=32/wave, 2-deep pipeline ----------------
// C = relu(A_bf16 @ B_bf16 + bias). Wave tile m=32 x n=64. WN waves across n; BM=32*(4/WN).

__global__ __launch_bounds__(256) void k_encb(const unsigned short* __restrict__ A,
                                              int M, int K, int WN,
                                              const unsigned short* __restrict__ BP,
                                              const float* __restrict__ bias,
                                              unsigned short* __restrict__ Cb,
                                              float* __restrict__ Cf, int ldc) {
    int t = threadIdx.x;
    int lane = t & 63;
    int l16 = lane & 15;
    int quad = lane >> 4;
    int w = t >> 6;
    int nw = w % WN;
    int mg = w / WN;
    int BM = 32 * (4 / WN);
    int bm = blockIdx.x * BM + mg * 32;
    int n0 = nw * 64;
    int NC = K >> 5;
    size_t cstr = (size_t)(ldc >> 6) * 2048;

    floatx4 acc[2][4];
#pragma unroll
    for (int i = 0; i < 2; ++i)
#pragma unroll
        for (int j = 0; j < 4; ++j) acc[i][j] = (floatx4)0.f;

    int r0 = bm + l16; if (r0 > M - 1) r0 = M - 1;
    int r1 = bm + 16 + l16; if (r1 > M - 1) r1 = M - 1;
    const unsigned short* a0 = A + (size_t)r0 * K + quad * 8;
    const unsigned short* a1 = A + (size_t)r1 * K + quad * 8;
    const unsigned short* bp = BP + ((size_t)(n0 >> 6) * 4) * 512 + lane * 8;

    // 2-slot fragment buffers (chunks c and c+1), prefetch distance 2
    short8 A0[2], A1[2], B[2][4];
#pragma unroll
    for (int s = 0; s < 2; ++s) {
        int cc = (s < NC) ? s : NC - 1;
        A0[s] = *(const short8*)(a0 + cc * 32);
        A1[s] = *(const short8*)(a1 + cc * 32);
#pragma unroll
        for (int j = 0; j < 4; ++j)
            B[s][j] = *(const short8*)(bp + (size_t)cc * cstr + j * 512);
    }

    for (int c = 0; c < NC; ++c) {
        int nc = (c + 2 < NC) ? c + 2 : NC - 1;
        short8 tA0 = *(const short8*)(a0 + nc * 32);
        short8 tA1 = *(const short8*)(a1 + nc * 32);
        short8 tB[4];
#pragma unroll
        for (int j = 0; j < 4; ++j)
            tB[j] = *(const short8*)(bp + (size_t)nc * cstr + j * 512);
#pragma unroll
        for (int j = 0; j < 4; ++j) {
            acc[0][j] = __builtin_amdgcn_mfma_f32_16x16x32_bf16(A0[0], B[0][j], acc[0][j], 0, 0, 0);
            acc[1][j] = __builtin_amdgcn_mfma_f32_16x16x32_bf16(A1[0], B[0][j], acc[1][j], 0, 0, 0);
        }
        A0[0] = A0[1]; A1[0] = A1[1];
#pragma unroll
        for (int j = 0; j < 4; ++j) B[0][j] = B[1][j];
        A0[1] = tA0; A1[1] = tA1;
#pragma unroll
        for (int j = 0; j < 4; ++j) B[1][j] = tB[j];
    }

#pragma unroll
    for (int i = 0; i < 2; ++i) {
#pragma unroll
        for (int r = 0; r < 4; ++r) {
            int m = bm + i * 16 + quad * 4 + r;
            if (m < M) {
#pragma unroll
                for (int j = 0; j < 4; ++j) {
                    float y = fmaxf(acc[i][j][r] + bias[n0 + j * 16 + l16], 0.f);
                    size_t idx = (size_t)m * ldc + n0 + j * 16 + l16;
                    if (Cb) Cb[idx] = f2bf(y);
                    else    Cf[idx] = y;
                }
            }
        }
    }
}

// ---------------- graph mean-pool ----------------

__global__ __launch_bounds__(256) void k_pool(const float* __restrict__ h2,
                                              const int* __restrict__ gstart,
                                              float* __restrict__ gsum, int H) {
    int g = blockIdx.x / SMAX;
    int s = blockIdx.x % SMAX;
    int base = gstart[g], end = gstart[g + 1];
    int cnt = end - base;
    if (cnt <= 0) return;
    int per = (cnt + SMAX - 1) / SMAX;
    int n0 = base + s * per;
    int n1 = n0 + per; if (n1 > end) n1 = end;
    if (n0 >= n1) return;
    int t = threadIdx.x;
    int q = t & 31;
    int c = q * 4;
    int sub = t >> 5;
    float4 acc = make_float4(0.f, 0.f, 0.f, 0.f);
    for (int n = n0 + sub; n < n1; n += 8) {
        float4 v = *(const float4*)(h2 + (size_t)n * H + c);
        acc.x += v.x; acc.y += v.y; acc.z += v.z; acc.w += v.w;
    }
    __shared__ float4 red[8][32];
    red[sub][q] = acc;
    __syncthreads();
    if (sub == 0) {
        float4 a = red[0][q];
#pragma unroll
        for (int i = 1; i < 8; ++i) {
            float4 b = red[i][q];
            a.x += b.x; a.y += b.y; a.z += b.z; a.w += b.w;
        }
        atomicAdd(&gsum[(size_t)g * H + c + 0], a.x);
        atomicAdd(&gsum[(size_t)g * H + c + 1], a.y);
        atomicAdd(&gsum[(size_t)g * H + c + 2], a.z);
        atomicAdd(&gsum[(size_t)g * H + c + 3], a.w);
    }
}

// ---------------- decoder ----------------

__global__ void k_dec(const float* __restrict__ gsum, const int* __restrict__ gstart,
                      const float* __restrict__ W1, const float* __restrict__ b1,
                      const float* __restrict__ W2, const float* __restrict__ b2,
                      float* __restrict__ out, int H, int HD) {
    int g = blockIdx.x;
    int t = threadIdx.x;
    float cnt = (float)(gstart[g + 1] - gstart[g]);
    float inv = 1.0f / fmaxf(cnt, 1.0f);
    float hid = b1[t];
    for (int k = 0; k < H; ++k) {
        float gf = gsum[(size_t)g * H + k] * inv;
        hid = fmaf(gf, W1[k * HD + t], hid);
    }
    hid = fmaxf(hid, 0.f);
    float p = hid * W2[t];
    for (int off = 32; off > 0; off >>= 1) p += __shfl_down(p, off);
    if (t == 0) out[g] = p + b2[0];
}

// ---------------- host ----------------

extern "C" void kernel_launch(void* const* d_in, const int* in_sizes, int n_in,
                              void* d_out, int out_size, void* d_ws, size_t ws_size,
                              hipStream_t stream) {
    const float* x     = (const float*)d_in[0];
    const int*   ei    = (const int*)d_in[1];
    const int*   batch = (const int*)d_in[2];
    const float* convW = (const float*)d_in[3];
    const float* convb = (const float*)d_in[4];
    const float* gamma = (const float*)d_in[5];
    const float* beta  = (const float*)d_in[6];
    const float* mean  = (const float*)d_in[7];
    const float* var   = (const float*)d_in[8];
    const float* eW1   = (const float*)d_in[9];
    const float* eb1   = (const float*)d_in[10];
    const float* eW2   = (const float*)d_in[11];
    const float* eb2   = (const float*)d_in[12];
    const float* dW1   = (const float*)d_in[13];
    const float* db1   = (const float*)d_in[14];
    const float* dW2   = (const float*)d_in[15];
    const float* db2   = (const float*)d_in[16];

    int N  = in_sizes[0] / D;
    int E  = in_sizes[1] / 2;
    int L  = in_sizes[3] / (D * D);
    int G  = out_size;
    int LD = L * D;                 // 256
    int H1 = in_sizes[10];          // 256
    int H2 = in_sizes[12];          // 128
    int HD = in_sizes[14];          // 64
    int NBK = (N + 255) >> 8;       // 391

    char* ws = (char*)d_ws;
    size_t off = 0;
    auto alloc = [&](size_t b) -> void* {
        void* p = ws + off;
        off += (b + 255) & ~(size_t)255;
        return p;
    };
    float* local  = (float*)alloc((size_t)N * LD * 4);        // fp32 layer outputs; later h2
    unsigned short* localb = (unsigned short*)alloc((size_t)N * LD * 2);  // bf16 copy (enc A + conv A)
    char*  bufB   = (char*)alloc((size_t)N * LD * 2);         // part / xw / h1b
    unsigned short* xb = (unsigned short*)alloc((size_t)N * D * 2);       // bf16 of x
    int*   csrc   = (int*)alloc((size_t)E * 4);
    float* dis    = (float*)alloc((size_t)N * 4);
    int*   offs   = (int*)alloc((size_t)(N + 1) * 4);
    int*   ghist  = (int*)alloc((size_t)NBK * 4);
    int*   bstart = (int*)alloc((size_t)(NBK + 1) * 4);
    int*   gcur   = (int*)alloc((size_t)NBK * 4);
    float* sc     = (float*)alloc((size_t)LD * 4);
    float* sh     = (float*)alloc((size_t)LD * 4);
    float* gsum   = (float*)alloc((size_t)G * H2 * 4);
    int*   gstart = (int*)alloc((size_t)(G + 1) * 4);
    unsigned short* w1p  = (unsigned short*)alloc((size_t)LD * H1 * 2);   // enc1 bf16 packed
    unsigned short* w2p  = (unsigned short*)alloc((size_t)H1 * H2 * 2);   // enc2 bf16 packed
    unsigned short* wchi = (unsigned short*)alloc((size_t)L * D * D * 2); // conv hi packed
    unsigned short* wclo = (unsigned short*)alloc((size_t)L * D * D * 2); // conv lo packed
    int2* part = (int2*)bufB;                    // dead before first conv
    _Float16* xw = (_Float16*)bufB;              // fp16 [N][64] message table
    unsigned short* h1b = (unsigned short*)bufB; // bf16 [N][256] after convs
    float* h2 = local;                           // fp32 [N][128]; local dead after enc1

    hipMemsetAsync(ghist, 0, (size_t)NBK * 4, stream);
    hipMemsetAsync(gsum, 0, (size_t)G * H2 * 4, stream);

    int nchunks = (E + 8191) / 8192;
    k_hist<<<nchunks, 256, NBK * 4, stream>>>(ei + E, ghist, E, NBK);
    k_bscan<<<1, 512, 0, stream>>>(ghist, bstart, gcur, offs, NBK, N, E);
    k_part<<<nchunks, 256, 2 * NBK * 4, stream>>>(ei, ei + E, gcur, part, E, NBK);
    k_bucket<<<NBK, 256, 0, stream>>>(part, bstart, offs, dis, csrc, N);
    k_gb<<<1, 128, 0, stream>>>(batch, gstart, N, G);
    k_bnprep<<<(LD + 255) / 256, 256, 0, stream>>>(convb, gamma, beta, mean, var, sc, sh, LD);
    k_wpackb<<<(LD * H1 + 255) / 256, 256, 0, stream>>>(eW1, w1p, LD, H1, 8);
    k_wpackb<<<(H1 * H2 + 255) / 256, 256, 0, stream>>>(eW2, w2p, H1, H2, 7);
    for (int l = 0; l < L; ++l)
        k_wpack<<<(D * D + 255) / 256, 256, 0, stream>>>(convW + (size_t)l * D * D,
                                                         wchi + (size_t)l * D * D,
                                                         wclo + (size_t)l * D * D, D, D, 6);
    k_cast<<<(N * D / 8 + 255) / 256, 256, 0, stream>>>(x, xb, N * D / 8);

    for (int l = 0; l < L; ++l) {
        const unsigned short* Ain = (l == 0) ? xb : (localb + (size_t)(l - 1) * D);
        int lda = (l == 0) ? D : LD;
        k_convm<<<(N + 127) / 128, 256, 0, stream>>>(Ain, lda,
                                                     wchi + (size_t)l * D * D,
                                                     wclo + (size_t)l * D * D,
                                                     dis, xw, N);
        const float* skip = (l % 2 == 0 && l != 0 && l != L - 1) ? (local + (size_t)(l - 2) * D) : nullptr;
        k_agg<<<(N + 3) / 4, 256, 0, stream>>>(xw, offs, csrc, dis, sc + (size_t)l * D,
                                               sh + (size_t)l * D, skip,
                                               local + (size_t)l * D, LD,
                                               localb + (size_t)l * D, N);
    }

    // enc1: A = localb bf16 [N][256] -> h1b bf16 [N][256]. WN=4 -> BM=32.
    k_encb<<<(N + 31) / 32, 256, 0, stream>>>(localb, N, LD, 4, w1p, eb1,
                                              h1b, nullptr, H1);
    // enc2: A = h1b -> h2 fp32 [N][128]. WN=2 -> BM=64.
    k_encb<<<(N + 63) / 64, 256, 0, stream>>>(h1b, N, H1, 2, w2p, eb2,
                                              nullptr, h2, H2);

    k_pool<<<G * SMAX, 256, 0, stream>>>(h2, gstart, gsum, H2);
    k_dec<<<G, HD, 0, stream>>>(gsum, gstart, dW1, db1, dW2, db2, (float*)d_out, H2, HD);
}